// Round 4
// baseline (274.309 us; speedup 1.0000x reference)
//
#include <hip/hip_runtime.h>

// ---------------- types ----------------
typedef __bf16 bf16x8 __attribute__((ext_vector_type(8)));
typedef float  f32x4  __attribute__((ext_vector_type(4)));
typedef unsigned short ushort8 __attribute__((ext_vector_type(8)));

#define B_ROWS 8192
#define IN_D   512
#define CTX_D  256
#define CENTER 512
#define MIN_D  768
#define FF_D   1024
#define RNN_D  1024
#define OUT_D  512
#define O2C_D  256
#define TOT_D  768

__device__ __forceinline__ unsigned short f2bf(float f) {
    unsigned int u = __builtin_bit_cast(unsigned int, f);
    u = (u + 0x7fff + ((u >> 16) & 1)) >> 16;   // RNE
    return (unsigned short)u;
}

__device__ __forceinline__ void load_lds16(const void* g, void* l) {
    __builtin_amdgcn_global_load_lds(
        (const __attribute__((address_space(1))) unsigned int*)g,
        (__attribute__((address_space(3))) unsigned int*)l, 16, 0, 0);
}

// ---------------- fused prep kernel ----------------
// blockIdx segments: [0,128) reduce_sq partials; [128,1984) weight cvt; [1984,10176) act cvt
__launch_bounds__(256)
__global__ void prep_all(const float* __restrict__ Wread, float* __restrict__ partials,
                         const float* __restrict__ Wpre, const float* __restrict__ Wx,
                         const float* __restrict__ Wh,  const float* __restrict__ Wpost,
                         unsigned short* __restrict__ WpreT, unsigned short* __restrict__ WxhT,
                         unsigned short* __restrict__ WpostT, unsigned short* __restrict__ WreadT,
                         const float* __restrict__ center, const float* __restrict__ inputs,
                         const float* __restrict__ mstate,
                         unsigned short* __restrict__ csB, unsigned short* __restrict__ miB,
                         unsigned short* __restrict__ rnB) {
    const int bid = blockIdx.x;
    const int tid = threadIdx.x;
    if (bid < 128) {
        // sum of squares of W_read, 1024 elems per block -> partials[bid]
        __shared__ float red[4];
        const float* p = Wread + bid * 1024 + tid * 4;
        f32x4 v = *(const f32x4*)p;
        float s = v[0]*v[0] + v[1]*v[1] + v[2]*v[2] + v[3]*v[3];
        #pragma unroll
        for (int off = 32; off > 0; off >>= 1) s += __shfl_down(s, off, 64);
        if ((tid & 63) == 0) red[tid >> 6] = s;
        __syncthreads();
        if (tid == 0) partials[bid] = red[0] + red[1] + red[2] + red[3];
        return;
    }
    if (bid < 1984) {
        int g = (bid - 128) * 256 + tid;
        const float* W; unsigned short* out; int N, ostride;
        if (g < 98304)        { W = Wpre;  out = WpreT;        N = 1024; ostride = 768;  }
        else if (g < 229376)  { g -= 98304;  W = Wx;    out = WxhT;        N = 1024; ostride = 2048; }
        else if (g < 360448)  { g -= 229376; W = Wh;    out = WxhT + 1024; N = 1024; ostride = 2048; }
        else if (g < 458752)  { g -= 360448; W = Wpost; out = WpostT;      N = 768;  ostride = 1024; }
        else                  { g -= 458752; W = Wread; out = WreadT;      N = 256;  ostride = 512;  }
        int n  = g % N;
        int kg = g / N;
        ushort8 o;
        #pragma unroll
        for (int j = 0; j < 8; ++j)
            o[j] = f2bf(W[(long)(kg * 8 + j) * N + n]);
        *(ushort8*)(out + (long)n * ostride + kg * 8) = o;
        return;
    }
    long g = (long)(bid - 1984) * 256 + tid;
    const float* src; unsigned short* dst; int logc, ostride;
    if (g < 524288)       { src = center; dst = csB;        logc = 9;  ostride = 512;  }
    else if (g < 1048576) { g -= 524288;  src = inputs; dst = miB;        logc = 9;  ostride = 768;  }
    else                  { g -= 1048576; src = mstate; dst = rnB + 1024; logc = 10; ostride = 2048; }
    long e = g * 8;
    long row = e >> logc;
    int  col = (int)(e & ((1 << logc) - 1));
    f32x4 v0 = *(const f32x4*)(src + e);
    f32x4 v1 = *(const f32x4*)(src + e + 4);
    ushort8 o;
    o[0] = f2bf(v0[0]); o[1] = f2bf(v0[1]); o[2] = f2bf(v0[2]); o[3] = f2bf(v0[3]);
    o[4] = f2bf(v1[0]); o[5] = f2bf(v1[1]); o[6] = f2bf(v1[2]); o[7] = f2bf(v1[3]);
    *(ushort8*)(dst + row * (long)ostride + col) = o;
}

// ---------------- GEMM ----------------
// C(M x N) = act(A(M x K) @ W^T(N x K)^T [+ bias][* scale])
// m97 structure: BM=BN=128, BK=32, 4 waves at 64x64 each (wm=wave&1, wn=wave>>1),
// 2-barrier K-loop, global_load_lds width-16 staging.
// Swizzle: 16B chunk (row, kg) stored at slot row*4 + (kg ^ (row&3)); staging
// thread c fetches kg = (c&3) ^ ((c>>2)&3); fragment read chunk = lr ^ (lc&3).
// Max 2-way granule aliasing -> conflict-free (m136).
// Grid: blockIdx.x = bn (fast) so consecutive blocks share the A row-block (L2 reuse).
// MODE 0: *clipscale (bias = 128 partials of sum(W^2)) -> bf16 outB   (context)
// MODE 1: bias+relu  -> bf16 outB                                      (pre)
// MODE 2: bias+tanh  -> bf16 outB + fp32 outF                          (rnn/h_new)
// MODE 3: bias+relu  -> fp32 split d_out                               (post)
template<int MODE>
__launch_bounds__(256, 2)
__global__ void gemm_bt(const unsigned short* __restrict__ A,
                        const unsigned short* __restrict__ Bt,
                        int K, const float* __restrict__ bias,
                        unsigned short* __restrict__ outB, int ldob,
                        float* __restrict__ outF, int ldof) {
    __shared__ alignas(16) unsigned short sA[128 * 32];
    __shared__ alignas(16) unsigned short sB[128 * 32];

    const int tid  = threadIdx.x;
    const int wave = tid >> 6;
    const int lane = tid & 63;
    const int bn = blockIdx.x, bm = blockIdx.y;
    const int wm = wave & 1, wn = wave >> 1;
    const int lr = lane >> 4;   // quad id 0..3
    const int lc = lane & 15;

    f32x4 acc[4][4] = {};

    long aoff[2], boff[2];
    #pragma unroll
    for (int j = 0; j < 2; ++j) {
        const int c   = tid + j * 256;
        const int row = c >> 2;
        const int kg  = (c & 3) ^ (row & 3);
        aoff[j] = (long)(bm * 128 + row) * K + kg * 8;
        boff[j] = (long)(bn * 128 + row) * K + kg * 8;
    }

    const int rsw = lr ^ (lc & 3);  // fragment-read chunk swizzle base

    for (int k0 = 0; k0 < K; k0 += 32) {
        #pragma unroll
        for (int j = 0; j < 2; ++j) {
            load_lds16(A  + aoff[j] + k0, (char*)sA + j * 4096 + wave * 1024);
            load_lds16(Bt + boff[j] + k0, (char*)sB + j * 4096 + wave * 1024);
        }
        __syncthreads();

        bf16x8 af[4], bfr[4];
        #pragma unroll
        for (int t = 0; t < 4; ++t) {
            const int ar = wm * 64 + t * 16 + lc;
            af[t]  = *(const bf16x8*)(sA + ar * 32 + ((lr ^ (ar & 3)) * 8));
            const int br = wn * 64 + t * 16 + lc;
            bfr[t] = *(const bf16x8*)(sB + br * 32 + ((lr ^ (br & 3)) * 8));
        }
        #pragma unroll
        for (int i = 0; i < 4; ++i)
            #pragma unroll
            for (int j2 = 0; j2 < 4; ++j2)
                acc[i][j2] = __builtin_amdgcn_mfma_f32_16x16x32_bf16(af[i], bfr[j2], acc[i][j2], 0, 0, 0);
        __syncthreads();
    }

    // epilogue: C/D layout col = lane&15, row = (lane>>4)*4 + r
    float sc = 1.f;
    if constexpr (MODE == 0) {
        float s = 0.f;
        for (int i = 0; i < 128; ++i) s += bias[i];   // partials of sum(W_read^2)
        sc = 1.f / fmaxf(sqrtf(s), 1.f);
    }
    #pragma unroll
    for (int tn = 0; tn < 4; ++tn) {
        const int gcol = bn * 128 + wn * 64 + tn * 16 + lc;
        float bv = 0.f;
        if constexpr (MODE != 0) bv = bias[gcol];
        #pragma unroll
        for (int tm = 0; tm < 4; ++tm) {
            const int grow0 = bm * 128 + wm * 64 + tm * 16 + lr * 4;
            #pragma unroll
            for (int r = 0; r < 4; ++r) {
                const long grow = grow0 + r;
                float v = acc[tm][tn][r];
                if constexpr (MODE == 0) v *= sc;
                else v += bv;
                if constexpr (MODE == 1 || MODE == 3) v = fmaxf(v, 0.f);
                if constexpr (MODE == 2) v = tanhf(v);
                if constexpr (MODE == 0 || MODE == 1 || MODE == 2)
                    outB[grow * (long)ldob + gcol] = f2bf(v);
                if constexpr (MODE == 2)
                    outF[grow * (long)ldof + gcol] = v;
                if constexpr (MODE == 3) {
                    if (gcol < OUT_D)
                        outF[grow * OUT_D + gcol] = v;
                    else
                        outF[(long)B_ROWS * OUT_D + grow * O2C_D + (gcol - OUT_D)] = v;
                }
            }
        }
    }
}

// ---------------- launch ----------------
extern "C" void kernel_launch(void* const* d_in, const int* in_sizes, int n_in,
                              void* d_out, int out_size, void* d_ws, size_t ws_size,
                              hipStream_t stream) {
    const float* inputs = (const float*)d_in[0];
    const float* center = (const float*)d_in[1];
    const float* mstate = (const float*)d_in[2];
    const float* W_read = (const float*)d_in[3];
    const float* W_pre  = (const float*)d_in[4];
    const float* b_pre  = (const float*)d_in[5];
    const float* Wx     = (const float*)d_in[6];
    const float* Wh     = (const float*)d_in[7];
    const float* b_rnn  = (const float*)d_in[8];
    const float* W_post = (const float*)d_in[9];
    const float* b_post = (const float*)d_in[10];
    float* out = (float*)d_out;

    char* ws = (char*)d_ws;
    float* partials = (float*)ws;                                  // 128 floats
    unsigned short* WreadT = (unsigned short*)(ws + 1024);         // 256 x 512
    unsigned short* WpreT  = WreadT + 256 * 512;                   // 1024 x 768
    unsigned short* WxhT   = WpreT  + 1024 * 768;                  // 1024 x 2048
    unsigned short* WpostT = WxhT   + (long)1024 * 2048;           // 768 x 1024
    unsigned short* csB    = WpostT + 768 * 1024;                  // 8192 x 512
    unsigned short* miB    = csB + (long)B_ROWS * CENTER;          // 8192 x 768  [inputs | ctx]
    unsigned short* rnB    = miB + (long)B_ROWS * MIN_D;           // 8192 x 2048 [rnn_in | ms]
    unsigned short* hB     = rnB + (long)B_ROWS * 2048;            // 8192 x 1024

    prep_all<<<10176, 256, 0, stream>>>(W_read, partials,
                                        W_pre, Wx, Wh, W_post,
                                        WpreT, WxhT, WpostT, WreadT,
                                        center, inputs, mstate, csB, miB, rnB);

    // L1: context = (cs @ W_read) * clipscale -> miB cols [512..767]
    gemm_bt<0><<<dim3(2, 64), 256, 0, stream>>>(csB, WreadT, 512, partials,
                                                miB + 512, MIN_D, nullptr, 0);
    // L2: rnn_in = relu(mi @ W_pre + b_pre) -> rnB cols [0..1023]
    gemm_bt<1><<<dim3(8, 64), 256, 0, stream>>>(miB, WpreT, 768, b_pre,
                                                rnB, 2048, nullptr, 0);
    // L3: h = tanh([rnn_in|ms] @ [Wx;Wh] + b_rnn) -> hB (bf16) + d_out region 2 (fp32)
    gemm_bt<2><<<dim3(8, 64), 256, 0, stream>>>(rnB, WxhT, 2048, b_rnn,
                                                hB, RNN_D,
                                                out + (long)B_ROWS * TOT_D, RNN_D);
    // L4: module_output = relu(h @ W_post + b_post) -> fp32 d_out regions 0/1
    gemm_bt<3><<<dim3(6, 64), 256, 0, stream>>>(hB, WpostT, 1024, b_post,
                                                nullptr, 0, out, 0);
}